// Round 5
// baseline (523.620 us; speedup 1.0000x reference)
//
#include <hip/hip_runtime.h>

#define S_LEN   2048
#define HID     4096
#define NH      32
#define NKV     8
#define HD      128
#define QKV_N   (NH*HD + 2*NKV*HD)   // 6144
#define WINDOW  1024

typedef unsigned short u16;
typedef short s8v  __attribute__((ext_vector_type(8)));
typedef short s4v  __attribute__((ext_vector_type(4)));
typedef float f4v  __attribute__((ext_vector_type(4)));

#define MFMA16x32(a, b, c) __builtin_amdgcn_mfma_f32_16x16x32_bf16(a, b, c, 0, 0, 0)

typedef __attribute__((address_space(1))) const unsigned int g_u32;
typedef __attribute__((address_space(3))) unsigned int l_u32;

__device__ __forceinline__ float bf2f(u16 h) {
  union { unsigned int u; float f; } x;
  x.u = ((unsigned int)h) << 16;
  return x.f;
}
__device__ __forceinline__ u16 f2bf(float f) {
  union { float f; unsigned int u; } x;
  x.f = f;
  unsigned int u = x.u;
  return (u16)((u + 0x7FFFu + ((u >> 16) & 1u)) >> 16);
}

// ---------------------------------------------------------------------------
// f32 -> bf16 elementwise. n multiple of 1024. grid = n/1024, block 256.
// ---------------------------------------------------------------------------
__global__ __launch_bounds__(256) void cvt_bf16(const float* __restrict__ in,
                                               u16* __restrict__ out) {
  int i = (blockIdx.x * 256 + threadIdx.x) * 4;
  float4 v = *(const float4*)&in[i];
  u16 h[4] = { f2bf(v.x), f2bf(v.y), f2bf(v.z), f2bf(v.w) };
  *(s4v*)&out[i] = *(const s4v*)h;
}

// ---------------------------------------------------------------------------
// Fused phase-A converts (one dispatch instead of two):
// blocks [0,24576): qkv_w -> wW;  [24576,32768): hidden -> hb.
// ---------------------------------------------------------------------------
__global__ __launch_bounds__(256) void cvt_fused(
    const float* __restrict__ hidden, const float* __restrict__ qkv_w,
    u16* __restrict__ hb, u16* __restrict__ wW) {
  int b = blockIdx.x;
  const float* in;
  u16* out;
  int i;
  if (b < 24576) { in = qkv_w;  out = wW; i = (b * 256 + threadIdx.x) * 4; }
  else           { in = hidden; out = hb; i = ((b - 24576) * 256 + threadIdx.x) * 4; }
  float4 v = *(const float4*)&in[i];
  u16 h[4] = { f2bf(v.x), f2bf(v.y), f2bf(v.z), f2bf(v.w) };
  *(s4v*)&out[i] = *(const s4v*)h;
}

// ---------------------------------------------------------------------------
// GEMM v5: C[M,N] = A[M,K](bf16) * B[N,K](bf16)^T + bias[N](f32)
//   BM=128, BN=256, BK=32; 256 threads = 4 waves (1M x 4N),
//   PER-WAVE TILE 128x64 (acc[8][4]).
// CHANGE vs round 4 (LDS-pipe model, validated against m201's 62%:
// 64x64/wave caps MfmaUtil at ~45% because frag reads = 0.5KB/MFMA;
// 128x64/wave -> 0.375KB/MFMA -> cap ~55%): same 3-deep ring, same
// counted vmcnt, same swizzle (measured 0 conflicts), same 24KB bufs
// (72KB total -> 2 blocks/CU = 8 waves/CU). __launch_bounds__(256,2)
// pins VGPR <= 256 (est ~200: acc 128 + frags 48 + addr).
// Staging now 6 gload_lds per tile (256 thr x 16B = 4KB/issue);
// steady wait = vmcnt(6) (two tiles x 6 in flight; oldest 6 = t+1).
// ---------------------------------------------------------------------------
template<int OUT_BF16>
__global__ __launch_bounds__(256, 2) void gemm_bt(
    const u16* __restrict__ A, const u16* __restrict__ B,
    const float* __restrict__ bias, void* __restrict__ Cp,
    int M, int N, int K)
{
  __shared__ __align__(16) char lds[3 * 24576];   // per buf: sA 8KB + sB 16KB
  const int tid  = threadIdx.x;
  const int lane = tid & 63;
  const int w    = tid >> 6;                      // wave = n-column owner
  const int ln   = lane & 15, quad = lane >> 4;
  const long mBase = (long)blockIdx.y * 128;
  const long nBase = (long)blockIdx.x * 256;
  const u16* Ab = A + mBase * (long)K;
  const u16* Bb = B + nBase * (long)K;
  const long rs = (long)K * 2;                    // row stride bytes

  f4v acc[8][4];
#pragma unroll
  for (int i = 0; i < 8; ++i)
#pragma unroll
    for (int j = 0; j < 4; ++j)
#pragma unroll
      for (int r = 0; r < 4; ++r) acc[i][j][r] = 0.0f;

  const int nt = K >> 5;                          // K-tiles of 32

  // stage tile: 6 gload_lds per wave (0-1 = A, 2-5 = B quarters).
  // LDS dest linear; global source inverse-swizzled (rule 21 both-sides).
  auto stage = [&](int tile) {
    char* base = lds + (tile % 3) * 24576;
    const int ktb = tile * 64;                    // byte col of K-tile
#pragma unroll
    for (int k = 0; k < 6; ++k) {
      const u16* gsrc = (k < 2) ? Ab : Bb;
      char* ldst      = (k < 2) ? base : (base + 8192);
      const int kk    = (k < 2) ? k : (k - 2);
      int o  = kk * 4096 + w * 1024 + lane * 16;  // linear region byte offset
      int o2 = o ^ ((o >> 3) & 0x30);             // inverse-swizzled source pos
      const char* gp = (const char*)gsrc + (long)(o2 >> 6) * rs + ktb + (o2 & 63);
      __builtin_amdgcn_global_load_lds((g_u32*)(const void*)gp,
                                       (l_u32*)(void*)(ldst + kk * 4096 + w * 1024),
                                       16, 0, 0);
    }
  };

  // prologue: tiles 0 and 1 in flight; tile 0 resident before loop.
  stage(0);
  stage(1);
  asm volatile("s_waitcnt vmcnt(6)" ::: "memory");
  __builtin_amdgcn_s_barrier();
  __builtin_amdgcn_sched_barrier(0);

  int bsel = 0;
  for (int t = 0; t < nt; ++t) {
    char* base = lds + bsel * 24576;
    if (t + 2 < nt) stage(t + 2);

    __builtin_amdgcn_s_setprio(1);
    s8v af[8], bf[4];
#pragma unroll
    for (int f = 0; f < 8; ++f) {
      int r = f * 16 + ln;
      int o = r * 64 + quad * 16;
      o ^= (o >> 3) & 0x30;                       // read-side swizzle
      af[f] = *(const s8v*)(base + o);
    }
#pragma unroll
    for (int j = 0; j < 4; ++j) {
      int r = w * 64 + j * 16 + ln;
      int o = r * 64 + quad * 16;
      o ^= (o >> 3) & 0x30;
      bf[j] = *(const s8v*)(base + 8192 + o);
    }
#pragma unroll
    for (int i = 0; i < 8; ++i)
#pragma unroll
      for (int j = 0; j < 4; ++j)
        acc[i][j] = MFMA16x32(af[i], bf[j], acc[i][j]);
    __builtin_amdgcn_s_setprio(0);

    // iteration-end sync: tile t+1 must be resident; tile t+2 stays in flight.
    if (t < nt - 2) {
      asm volatile("s_waitcnt vmcnt(6)" ::: "memory");
      __builtin_amdgcn_s_barrier();
      __builtin_amdgcn_sched_barrier(0);
    } else if (t == nt - 2) {
      asm volatile("s_waitcnt vmcnt(0)" ::: "memory");
      __builtin_amdgcn_s_barrier();
      __builtin_amdgcn_sched_barrier(0);
    }
    bsel = (bsel == 2) ? 0 : bsel + 1;
  }

#pragma unroll
  for (int i = 0; i < 8; ++i) {
    long rowb = mBase + i * 16 + quad * 4;
#pragma unroll
    for (int j = 0; j < 4; ++j) {
      long col = nBase + w * 64 + j * 16 + ln;
      float bv = bias[col];
#pragma unroll
      for (int r = 0; r < 4; ++r) {
        float v = acc[i][j][r] + bv;
        if (OUT_BF16) ((u16*)Cp)[(rowb + r) * (long)N + col] = f2bf(v);
        else          ((float*)Cp)[(rowb + r) * (long)N + col] = v;
      }
    }
  }
}

// ---------------------------------------------------------------------------
// RoPE (YaRN, NEOX) on bf16 qkv; SCALE folded into q. One block per position.
// ---------------------------------------------------------------------------
__global__ __launch_bounds__(256) void rope_split(
    const u16* __restrict__ qkv, const int* __restrict__ positions,
    u16* __restrict__ qo, u16* __restrict__ ko, u16* __restrict__ vo)
{
  const int s = blockIdx.x;
  const int t = threadIdx.x;
  __shared__ float csh[64], snh[64];

  if (t < 64) {
    const double LN_BASE = log(500000.0);
    const double TWO_PI  = 6.283185307179586476925287;
    double cf  = 128.0 * log(32768.0 / (32.0 * TWO_PI)) / (2.0 * LN_BASE);
    double cs_ = 128.0 * log(32768.0 / TWO_PI) / (2.0 * LN_BASE);
    double lowd  = floor(cf);  if (lowd < 0.0)  lowd = 0.0;
    double highd = ceil(cs_);  if (highd > 63.0) highd = 63.0;
    double denom = highd - lowd; if (denom < 0.001) denom = 0.001;
    double d = (double)t;
    double inv_extra = exp(-LN_BASE * d / 64.0);
    double inv_inter = inv_extra * 0.25;
    double ramp = (d - lowd) / denom;
    ramp = ramp < 0.0 ? 0.0 : (ramp > 1.0 ? 1.0 : ramp);
    double maskv = 1.0 - ramp;
    double invf = inv_inter * (1.0 - maskv) + inv_extra * maskv;
    float freq = (float)positions[s] * (float)invf;
    const float msc = 1.1386294361119891f;
    csh[t] = cosf(freq) * msc;
    snh[t] = sinf(freq) * msc;
  }
  __syncthreads();

  const u16* row = qkv + (size_t)s * QKV_N;
  const float SC = 0.08838834764831845f;      // 128^-0.5

#pragma unroll
  for (int i = 0; i < 8; ++i) {
    int p = i * 256 + t;
    int hh = p >> 6, d = p & 63;
    float x1 = bf2f(row[hh * 128 + d]), x2 = bf2f(row[hh * 128 + d + 64]);
    float c = csh[d], sn = snh[d];
    qo[(size_t)s * 4096 + hh * 128 + d]      = f2bf((x1 * c - x2 * sn) * SC);
    qo[(size_t)s * 4096 + hh * 128 + d + 64] = f2bf((x2 * c + x1 * sn) * SC);
  }
#pragma unroll
  for (int i = 0; i < 2; ++i) {
    int p = i * 256 + t;
    int hh = p >> 6, d = p & 63;
    float x1 = bf2f(row[4096 + hh * 128 + d]), x2 = bf2f(row[4096 + hh * 128 + d + 64]);
    float c = csh[d], sn = snh[d];
    ko[(size_t)s * 1024 + hh * 128 + d]      = f2bf(x1 * c - x2 * sn);
    ko[(size_t)s * 1024 + hh * 128 + d + 64] = f2bf(x2 * c + x1 * sn);
  }
#pragma unroll
  for (int i = 0; i < 4; ++i) {
    int e = i * 256 + t;
    vo[(size_t)s * 1024 + e] = row[5120 + e];   // plain copy (already bf16)
  }
}

// ---------------------------------------------------------------------------
// V transpose: vb[2048][1024] -> vt[1024][2048] (u16). 64x64 tiles via LDS.
// grid (2048/64, 1024/64) = (32, 16), block 256.
// ---------------------------------------------------------------------------
__global__ __launch_bounds__(256) void transpose_v(const u16* __restrict__ vb,
                                                   u16* __restrict__ vt) {
  __shared__ u16 tile[64][72];
  const int s0 = blockIdx.x * 64, c0 = blockIdx.y * 64;
  const int tid = threadIdx.x;
#pragma unroll
  for (int t = 0; t < 2; ++t) {
    int row = t * 32 + (tid >> 3), col = (tid & 7) * 8;
    *(s8v*)&tile[row][col] = *(const s8v*)&vb[(size_t)(s0 + row) * 1024 + c0 + col];
  }
  __syncthreads();
#pragma unroll
  for (int t = 0; t < 2; ++t) {
    int orow = t * 32 + (tid >> 3), ocol = (tid & 7) * 8;
    u16 v[8];
#pragma unroll
    for (int e = 0; e < 8; ++e) v[e] = tile[ocol + e][orow];
    *(s8v*)&vt[(size_t)(c0 + orow) * 2048 + s0 + ocol] = *(const s8v*)v;
  }
}

// ---------------------------------------------------------------------------
// Flash attention v2.1: round-0 structure + (a) wave-local sP/sO syncs
// replaced by lgkmcnt(0)+sched_barrier (rule 18; sP[w] and own sO rows are
// strictly per-wave; cross-wave hazards remain guarded by the top-of-loop
// and pre-epilogue __syncthreads), (b) T5 setprio around MFMA clusters.
// ---------------------------------------------------------------------------
__global__ __launch_bounds__(256) void attn_fwd(
    const u16* __restrict__ Q, const u16* __restrict__ Kb,
    const u16* __restrict__ Vt, const float* __restrict__ sinks,
    u16* __restrict__ O)
{
  const int h = blockIdx.y, kvh = h >> 2;
  const int q0 = blockIdx.x * 64;
  const int tid = threadIdx.x, w = tid >> 6, lane = tid & 63;
  const int ln = lane & 15, quad = lane >> 4;
  const int qw = q0 + w * 16;        // wave's first query
  const int qi = qw + ln;            // this lane's query (n-index)

  __shared__ __align__(16) u16 sK[64 * 136];
  __shared__ __align__(16) u16 sVt[128 * 72];
  __shared__ __align__(16) u16 sP[4][16 * 72];

  // Q B-fragments: lane ln = q row; k = d (quad*8+j per 32-chunk)
  s8v qf[4];
  {
    const u16* qrow = Q + (size_t)qi * 4096 + h * 128;
#pragma unroll
    for (int kb = 0; kb < 4; ++kb)
      qf[kb] = *(const s8v*)&qrow[kb * 32 + quad * 8];
  }

  float m_v = sinks[h], l_v = 1.0f;
  f4v accO[8];
#pragma unroll
  for (int j = 0; j < 8; ++j)
#pragma unroll
    for (int r = 0; r < 4; ++r) accO[j][r] = 0.0f;

  int lo = q0 - (WINDOW - 1); if (lo < 0) lo = 0; lo &= ~63;

  for (int kt = lo; kt <= q0; kt += 64) {
    __syncthreads();                 // prev PV done before restaging
    // stage K tile: 64 keys x 128 dims, stride 136  (1024 chunks of 8 u16)
#pragma unroll
    for (int t = 0; t < 4; ++t) {
      int c = t * 256 + tid;
      int row = c >> 4, col = (c & 15) * 8;
      *(s8v*)&sK[row * 136 + col] =
          *(const s8v*)&Kb[(size_t)(kt + row) * 1024 + kvh * 128 + col];
    }
    // stage V^T tile: 128 dims x 64 keys, stride 72 (1024 chunks of 8 u16)
#pragma unroll
    for (int t = 0; t < 4; ++t) {
      int c = t * 256 + tid;
      int row = c >> 3, col = (c & 7) * 8;
      *(s8v*)&sVt[row * 72 + col] =
          *(const s8v*)&Vt[(size_t)(kvh * 128 + row) * 2048 + kt + col];
    }
    __syncthreads();

    // scores^T for 4 half-tiles of 16 keys: element (key=quad*4+r, q=ln)
    f4v sc[4];
    bool dead[4];
#pragma unroll
    for (int h4 = 0; h4 < 4; ++h4) {
      const int kb16 = kt + h4 * 16;
      dead[h4] = (kb16 > qw + 15) || (kb16 + 15 < qw - (WINDOW - 1));
      if (dead[h4]) {
#pragma unroll
        for (int r = 0; r < 4; ++r) sc[h4][r] = -1e30f;
        continue;
      }
      f4v s;
#pragma unroll
      for (int r = 0; r < 4; ++r) s[r] = 0.0f;
      __builtin_amdgcn_s_setprio(1);
#pragma unroll
      for (int kb = 0; kb < 4; ++kb) {
        s8v kf = *(const s8v*)&sK[(h4 * 16 + ln) * 136 + kb * 32 + quad * 8];
        s = MFMA16x32(kf, qf[kb], s);   // A=K rows (m=key), B=Q (n=q)
      }
      __builtin_amdgcn_s_setprio(0);
      const bool full = (kb16 + 15 <= qw) && (qw + 15 - kb16 <= WINDOW - 1);
      if (!full) {
        int base = qi - kb16 - quad * 4;   // qi - key for r=0
#pragma unroll
        for (int r = 0; r < 4; ++r)
          s[r] = ((unsigned)(base - r) <= (WINDOW - 1)) ? s[r] : -1e30f;
      }
      sc[h4] = s;
    }

    // online softmax: per-lane column q=ln; reduce 16 in-lane + 2 shfl
    float mn = m_v;
#pragma unroll
    for (int h4 = 0; h4 < 4; ++h4)
#pragma unroll
      for (int r = 0; r < 4; ++r) mn = fmaxf(mn, sc[h4][r]);
    mn = fmaxf(mn, __shfl_xor(mn, 16));
    mn = fmaxf(mn, __shfl_xor(mn, 32));

    float alpha = __expf(m_v - mn);
    m_v = mn;
    l_v *= alpha;
#pragma unroll
    for (int j = 0; j < 8; ++j)
#pragma unroll
      for (int r = 0; r < 4; ++r) accO[j][r] *= alpha;

    float lsum = 0.0f;
#pragma unroll
    for (int h4 = 0; h4 < 4; ++h4) {
      float p[4];
#pragma unroll
      for (int r = 0; r < 4; ++r) p[r] = __expf(sc[h4][r] - mn);
      lsum += (p[0] + p[1]) + (p[2] + p[3]);
      u16 pb[4] = { f2bf(p[0]), f2bf(p[1]), f2bf(p[2]), f2bf(p[3]) };
      *(s4v*)&sP[w][ln * 72 + h4 * 16 + quad * 4] = *(const s4v*)pb;
    }
    lsum += __shfl_xor(lsum, 16);
    lsum += __shfl_xor(lsum, 32);
    l_v += lsum;

    // sP is per-wave: within-wave DS write->read ordering only (rule 18)
    asm volatile("s_waitcnt lgkmcnt(0)" ::: "memory");
    __builtin_amdgcn_sched_barrier(0);

    // PV: A = V^T rows (m=d), B = P (n=q), k = 32-key chunks
#pragma unroll
    for (int c2 = 0; c2 < 2; ++c2) {
      if (dead[2 * c2] && dead[2 * c2 + 1]) continue;
      s8v pf = *(const s8v*)&sP[w][ln * 72 + c2 * 32 + quad * 8];
      __builtin_amdgcn_s_setprio(1);
#pragma unroll
      for (int j = 0; j < 8; ++j) {
        s8v vf = *(const s8v*)&sVt[(j * 16 + ln) * 72 + c2 * 32 + quad * 8];
        accO[j] = MFMA16x32(vf, pf, accO[j]);
      }
      __builtin_amdgcn_s_setprio(0);
    }
  }

  // epilogue: O^T (d rows, q cols) -> LDS transpose -> coalesced store
  __syncthreads();                    // all waves done with sK/sVt (cross-wave)
  u16* sO = sK;                       // reuse: [64 q-rows][136]
  const float rl = 1.0f / l_v;
#pragma unroll
  for (int j = 0; j < 8; ++j) {
    u16 ob[4] = { f2bf(accO[j][0] * rl), f2bf(accO[j][1] * rl),
                  f2bf(accO[j][2] * rl), f2bf(accO[j][3] * rl) };
    *(s4v*)&sO[(w * 16 + ln) * 136 + j * 16 + quad * 4] = *(const s4v*)ob;
  }
  // readback touches only this wave's rows: wave-local ordering suffices
  asm volatile("s_waitcnt lgkmcnt(0)" ::: "memory");
  __builtin_amdgcn_sched_barrier(0);
  {
    int row = lane >> 2, cc = lane & 3;
#pragma unroll
    for (int i = 0; i < 4; ++i) {
      s8v v = *(const s8v*)&sO[(w * 16 + row) * 136 + cc * 8 + i * 32];
      *(s8v*)&O[(size_t)(q0 + w * 16 + row) * 4096 + h * 128 + cc * 8 + i * 32] = v;
    }
  }
}

// ---------------------------------------------------------------------------
// Launch. Workspace peak = 92,274,688 B (round-2 proven footprint).
// Phase-aliased layout:
//   Region X [0, 48 MB):       qkv_w bf16 (dies after gemm1)
//                              -> qb@0 kb@16M vb@20M vt@24M attn@28M (45 MB)
//   Region Y [48 MB, 88 MB):   hidden bf16 @48M + qkvb @64M (dies after rope)
//                              -> o_w bf16 @48M (32 MB)
// ---------------------------------------------------------------------------
extern "C" void kernel_launch(void* const* d_in, const int* in_sizes, int n_in,
                              void* d_out, int out_size, void* d_ws, size_t ws_size,
                              hipStream_t stream) {
  const float* hidden    = (const float*)d_in[0];
  const int*   positions = (const int*)d_in[1];
  const float* qkv_w     = (const float*)d_in[2];
  const float* qkv_b     = (const float*)d_in[3];
  const float* o_w       = (const float*)d_in[4];
  const float* o_b       = (const float*)d_in[5];
  const float* sinks     = (const float*)d_in[6];

  char* ws = (char*)d_ws;
  // Region X
  u16* wW   = (u16*)ws;                         // 48 MB (phase A)
  u16* qb   = (u16*)ws;                         // 16 MB (phase B)
  u16* kb   = (u16*)(ws + 16777216ull);         //  4 MB
  u16* vb   = (u16*)(ws + 20971520ull);         //  4 MB
  u16* vt   = (u16*)(ws + 25165824ull);         //  4 MB
  u16* attn = (u16*)(ws + 29360128ull);         // 16 MB (ends 45 MB)
  // Region Y
  u16* hb   = (u16*)(ws + 50331648ull);         // 16 MB (phase A)
  u16* qkvb = (u16*)(ws + 67108864ull);         // 24 MB (ends 92,274,688)
  u16* oWb  = (u16*)(ws + 50331648ull);         // 32 MB (phase B, ends 84 MB)

  cvt_fused<<<32768, 256, 0, stream>>>(hidden, qkv_w, hb, wW);

  gemm_bt<1><<<dim3(QKV_N / 256, S_LEN / 128), 256, 0, stream>>>(
      hb, wW, qkv_b, (void*)qkvb, S_LEN, QKV_N, HID);   // wW, hb die here

  rope_split<<<S_LEN, 256, 0, stream>>>(qkvb, positions, qb, kb, vb); // qkvb dies

  cvt_bf16<<<16384, 256, 0, stream>>>(o_w, oWb);        // 4096*4096, region Y reuse

  transpose_v<<<dim3(32, 16), 256, 0, stream>>>(vb, vt);

  attn_fwd<<<dim3(S_LEN / 64, NH), 256, 0, stream>>>(qb, kb, vt, sinks, attn);

  gemm_bt<0><<<dim3(HID / 256, S_LEN / 128), 256, 0, stream>>>(
      attn, oWb, o_b, d_out, S_LEN, HID, HID);
}

// Round 6
// 507.695 us; speedup vs baseline: 1.0314x; 1.0314x over previous
//
#include <hip/hip_runtime.h>

#define S_LEN   2048
#define HID     4096
#define NH      32
#define NKV     8
#define HD      128
#define QKV_N   (NH*HD + 2*NKV*HD)   // 6144
#define WINDOW  1024

typedef unsigned short u16;
typedef short s8v  __attribute__((ext_vector_type(8)));
typedef short s4v  __attribute__((ext_vector_type(4)));
typedef float f4v  __attribute__((ext_vector_type(4)));

#define MFMA16x32(a, b, c) __builtin_amdgcn_mfma_f32_16x16x32_bf16(a, b, c, 0, 0, 0)

typedef __attribute__((address_space(1))) const unsigned int g_u32;
typedef __attribute__((address_space(3))) unsigned int l_u32;

__device__ __forceinline__ float bf2f(u16 h) {
  union { unsigned int u; float f; } x;
  x.u = ((unsigned int)h) << 16;
  return x.f;
}
__device__ __forceinline__ u16 f2bf(float f) {
  union { float f; unsigned int u; } x;
  x.f = f;
  unsigned int u = x.u;
  return (u16)((u + 0x7FFFu + ((u >> 16) & 1u)) >> 16);
}

// ---------------------------------------------------------------------------
// f32 -> bf16 elementwise. n multiple of 1024. grid = n/1024, block 256.
// ---------------------------------------------------------------------------
__global__ __launch_bounds__(256) void cvt_bf16(const float* __restrict__ in,
                                               u16* __restrict__ out) {
  int i = (blockIdx.x * 256 + threadIdx.x) * 4;
  float4 v = *(const float4*)&in[i];
  u16 h[4] = { f2bf(v.x), f2bf(v.y), f2bf(v.z), f2bf(v.w) };
  *(s4v*)&out[i] = *(const s4v*)h;
}

// ---------------------------------------------------------------------------
// Fused phase-A converts (one dispatch instead of two):
// blocks [0,24576): qkv_w -> wW;  [24576,32768): hidden -> hb.
// ---------------------------------------------------------------------------
__global__ __launch_bounds__(256) void cvt_fused(
    const float* __restrict__ hidden, const float* __restrict__ qkv_w,
    u16* __restrict__ hb, u16* __restrict__ wW) {
  int b = blockIdx.x;
  const float* in;
  u16* out;
  int i;
  if (b < 24576) { in = qkv_w;  out = wW; i = (b * 256 + threadIdx.x) * 4; }
  else           { in = hidden; out = hb; i = ((b - 24576) * 256 + threadIdx.x) * 4; }
  float4 v = *(const float4*)&in[i];
  u16 h[4] = { f2bf(v.x), f2bf(v.y), f2bf(v.z), f2bf(v.w) };
  *(s4v*)&out[i] = *(const s4v*)h;
}

// ---------------------------------------------------------------------------
// GEMM v4 (ROUND-4 VERBATIM, the best verified config: g1=122us, MfmaUtil 36,
// 0 bank conflicts, 2 blocks/CU = 16 waves/CU):
//   BM=128, BN=256, BK=32; 512 threads = 8 waves (2M x 4N), 64x64 per wave.
//   3-deep ring (72KB LDS), counted vmcnt(3) (T4, never 0 mid-loop),
//   3-bit XOR swizzle o^=((o>>3)&0x30) both-sides (rule 21).
// Round-5 lesson: 128x64/wave at 256thr halved waves/CU -> regressed;
// in this barrier-per-tile structure waves/CU dominates bytes/MFMA.
// ---------------------------------------------------------------------------
template<int OUT_BF16>
__global__ __launch_bounds__(512, 4) void gemm_bt(
    const u16* __restrict__ A, const u16* __restrict__ B,
    const float* __restrict__ bias, void* __restrict__ Cp,
    int M, int N, int K)
{
  __shared__ __align__(16) char lds[3 * 24576];   // per buf: sA 8KB + sB 16KB
  const int tid  = threadIdx.x;
  const int lane = tid & 63;
  const int w    = tid >> 6;
  const int wm   = w >> 2, wn = w & 3;
  const int ln   = lane & 15, quad = lane >> 4;
  const long mBase = (long)blockIdx.y * 128;
  const long nBase = (long)blockIdx.x * 256;
  const u16* Ab = A + mBase * (long)K;
  const u16* Bb = B + nBase * (long)K;
  const long rs = (long)K * 2;                    // row stride bytes

  f4v acc[4][4];
#pragma unroll
  for (int i = 0; i < 4; ++i)
#pragma unroll
    for (int j = 0; j < 4; ++j)
#pragma unroll
      for (int r = 0; r < 4; ++r) acc[i][j][r] = 0.0f;

  const int nt = K >> 5;                          // K-tiles of 32

  auto stage = [&](int tile) {
    char* base = lds + (tile % 3) * 24576;
    const int ktb = tile * 64;                    // byte col of K-tile
#pragma unroll
    for (int k = 0; k < 3; ++k) {
      const u16* gsrc = (k == 0) ? Ab : Bb;
      char* ldst      = (k == 0) ? base : (base + 8192);
      const int kk    = (k == 0) ? 0 : (k - 1);
      int o  = kk * 8192 + w * 1024 + lane * 16;  // linear region byte offset
      int o2 = o ^ ((o >> 3) & 0x30);             // inverse-swizzled source pos
      const char* gp = (const char*)gsrc + (long)(o2 >> 6) * rs + ktb + (o2 & 63);
      __builtin_amdgcn_global_load_lds((g_u32*)(const void*)gp,
                                       (l_u32*)(void*)(ldst + kk * 8192 + w * 1024),
                                       16, 0, 0);
    }
  };

  stage(0);
  stage(1);
  asm volatile("s_waitcnt vmcnt(3)" ::: "memory");
  __builtin_amdgcn_s_barrier();
  __builtin_amdgcn_sched_barrier(0);

  int bsel = 0;
  for (int t = 0; t < nt; ++t) {
    char* base = lds + bsel * 24576;
    if (t + 2 < nt) stage(t + 2);

    __builtin_amdgcn_s_setprio(1);
    s8v af[4], bf[4];
#pragma unroll
    for (int f = 0; f < 4; ++f) {
      int r = wm * 64 + f * 16 + ln;
      int o = r * 64 + quad * 16;
      o ^= (o >> 3) & 0x30;                       // read-side swizzle
      af[f] = *(const s8v*)(base + o);
    }
#pragma unroll
    for (int j = 0; j < 4; ++j) {
      int r = wn * 64 + j * 16 + ln;
      int o = r * 64 + quad * 16;
      o ^= (o >> 3) & 0x30;
      bf[j] = *(const s8v*)(base + 8192 + o);
    }
#pragma unroll
    for (int i = 0; i < 4; ++i)
#pragma unroll
      for (int j = 0; j < 4; ++j)
        acc[i][j] = MFMA16x32(af[i], bf[j], acc[i][j]);
    __builtin_amdgcn_s_setprio(0);

    if (t < nt - 2) {
      asm volatile("s_waitcnt vmcnt(3)" ::: "memory");
      __builtin_amdgcn_s_barrier();
      __builtin_amdgcn_sched_barrier(0);
    } else if (t == nt - 2) {
      asm volatile("s_waitcnt vmcnt(0)" ::: "memory");
      __builtin_amdgcn_s_barrier();
      __builtin_amdgcn_sched_barrier(0);
    }
    bsel = (bsel == 2) ? 0 : bsel + 1;
  }

#pragma unroll
  for (int i = 0; i < 4; ++i) {
    long rowb = mBase + wm * 64 + i * 16 + quad * 4;
#pragma unroll
    for (int j = 0; j < 4; ++j) {
      long col = nBase + wn * 64 + j * 16 + ln;
      float bv = bias[col];
#pragma unroll
      for (int r = 0; r < 4; ++r) {
        float v = acc[i][j][r] + bv;
        if (OUT_BF16) ((u16*)Cp)[(rowb + r) * (long)N + col] = f2bf(v);
        else          ((float*)Cp)[(rowb + r) * (long)N + col] = v;
      }
    }
  }
}

// ---------------------------------------------------------------------------
// RoPE (YaRN, NEOX) on bf16 qkv; SCALE folded into q. One block per position.
// V-copy removed: transpose_v now reads V straight from qkvb.
// ---------------------------------------------------------------------------
__global__ __launch_bounds__(256) void rope_split(
    const u16* __restrict__ qkv, const int* __restrict__ positions,
    u16* __restrict__ qo, u16* __restrict__ ko)
{
  const int s = blockIdx.x;
  const int t = threadIdx.x;
  __shared__ float csh[64], snh[64];

  if (t < 64) {
    const double LN_BASE = log(500000.0);
    const double TWO_PI  = 6.283185307179586476925287;
    double cf  = 128.0 * log(32768.0 / (32.0 * TWO_PI)) / (2.0 * LN_BASE);
    double cs_ = 128.0 * log(32768.0 / TWO_PI) / (2.0 * LN_BASE);
    double lowd  = floor(cf);  if (lowd < 0.0)  lowd = 0.0;
    double highd = ceil(cs_);  if (highd > 63.0) highd = 63.0;
    double denom = highd - lowd; if (denom < 0.001) denom = 0.001;
    double d = (double)t;
    double inv_extra = exp(-LN_BASE * d / 64.0);
    double inv_inter = inv_extra * 0.25;
    double ramp = (d - lowd) / denom;
    ramp = ramp < 0.0 ? 0.0 : (ramp > 1.0 ? 1.0 : ramp);
    double maskv = 1.0 - ramp;
    double invf = inv_inter * (1.0 - maskv) + inv_extra * maskv;
    float freq = (float)positions[s] * (float)invf;
    const float msc = 1.1386294361119891f;
    csh[t] = cosf(freq) * msc;
    snh[t] = sinf(freq) * msc;
  }
  __syncthreads();

  const u16* row = qkv + (size_t)s * QKV_N;
  const float SC = 0.08838834764831845f;      // 128^-0.5

#pragma unroll
  for (int i = 0; i < 8; ++i) {
    int p = i * 256 + t;
    int hh = p >> 6, d = p & 63;
    float x1 = bf2f(row[hh * 128 + d]), x2 = bf2f(row[hh * 128 + d + 64]);
    float c = csh[d], sn = snh[d];
    qo[(size_t)s * 4096 + hh * 128 + d]      = f2bf((x1 * c - x2 * sn) * SC);
    qo[(size_t)s * 4096 + hh * 128 + d + 64] = f2bf((x2 * c + x1 * sn) * SC);
  }
#pragma unroll
  for (int i = 0; i < 2; ++i) {
    int p = i * 256 + t;
    int hh = p >> 6, d = p & 63;
    float x1 = bf2f(row[4096 + hh * 128 + d]), x2 = bf2f(row[4096 + hh * 128 + d + 64]);
    float c = csh[d], sn = snh[d];
    ko[(size_t)s * 1024 + hh * 128 + d]      = f2bf(x1 * c - x2 * sn);
    ko[(size_t)s * 1024 + hh * 128 + d + 64] = f2bf(x2 * c + x1 * sn);
  }
}

// ---------------------------------------------------------------------------
// V transpose from qkvb: qkvb[s][5120+c] -> vt[c][s] (u16). 64x64 tiles.
// grid (2048/64, 1024/64) = (32, 16), block 256. Must run BEFORE cvt(o_w)
// (oWb region overlaps qkvb).
// ---------------------------------------------------------------------------
__global__ __launch_bounds__(256) void transpose_v(const u16* __restrict__ qkvb,
                                                   u16* __restrict__ vt) {
  __shared__ u16 tile[64][72];
  const int s0 = blockIdx.x * 64, c0 = blockIdx.y * 64;
  const int tid = threadIdx.x;
#pragma unroll
  for (int t = 0; t < 2; ++t) {
    int row = t * 32 + (tid >> 3), col = (tid & 7) * 8;
    *(s8v*)&tile[row][col] =
        *(const s8v*)&qkvb[(size_t)(s0 + row) * QKV_N + 5120 + c0 + col];
  }
  __syncthreads();
#pragma unroll
  for (int t = 0; t < 2; ++t) {
    int orow = t * 32 + (tid >> 3), ocol = (tid & 7) * 8;
    u16 v[8];
#pragma unroll
    for (int e = 0; e < 8; ++e) v[e] = tile[ocol + e][orow];
    *(s8v*)&vt[(size_t)(c0 + orow) * 2048 + s0 + ocol] = *(const s8v*)v;
  }
}

// ---------------------------------------------------------------------------
// Flash attention v2.2: round-5 structure + T14 async-STAGE split (m214
// r277, +17%): next K/V tile is loaded into REGISTERS right after the
// compute-side barrier (flies under QK/softmax/PV), ds_written at the next
// loop-top. The post-write barrier is lgkmcnt(0) + RAW s_barrier -- NOT
// __syncthreads(), which would emit vmcnt(0) and drain the in-flight
// prefetch (the m97 barrier-drain trap). Numerics order-identical.
// ---------------------------------------------------------------------------
__global__ __launch_bounds__(256) void attn_fwd(
    const u16* __restrict__ Q, const u16* __restrict__ Kb,
    const u16* __restrict__ Vt, const float* __restrict__ sinks,
    u16* __restrict__ O)
{
  const int h = blockIdx.y, kvh = h >> 2;
  const int q0 = blockIdx.x * 64;
  const int tid = threadIdx.x, w = tid >> 6, lane = tid & 63;
  const int ln = lane & 15, quad = lane >> 4;
  const int qw = q0 + w * 16;        // wave's first query
  const int qi = qw + ln;            // this lane's query (n-index)

  __shared__ __align__(16) u16 sK[64 * 136];
  __shared__ __align__(16) u16 sVt[128 * 72];
  __shared__ __align__(16) u16 sP[4][16 * 72];

  // Q B-fragments: lane ln = q row; k = d (quad*8+j per 32-chunk)
  s8v qf[4];
  {
    const u16* qrow = Q + (size_t)qi * 4096 + h * 128;
#pragma unroll
    for (int kb = 0; kb < 4; ++kb)
      qf[kb] = *(const s8v*)&qrow[kb * 32 + quad * 8];
  }

  float m_v = sinks[h], l_v = 1.0f;
  f4v accO[8];
#pragma unroll
  for (int j = 0; j < 8; ++j)
#pragma unroll
    for (int r = 0; r < 4; ++r) accO[j][r] = 0.0f;

  int lo = q0 - (WINDOW - 1); if (lo < 0) lo = 0; lo &= ~63;

  // T14 register staging: issue tile `lo` now.
  s8v kreg[4], vreg[4];
#pragma unroll
  for (int t = 0; t < 4; ++t) {
    int c = t * 256 + tid, row = c >> 4, col = (c & 15) * 8;
    kreg[t] = *(const s8v*)&Kb[(size_t)(lo + row) * 1024 + kvh * 128 + col];
  }
#pragma unroll
  for (int t = 0; t < 4; ++t) {
    int c = t * 256 + tid, row = c >> 3, col = (c & 7) * 8;
    vreg[t] = *(const s8v*)&Vt[(size_t)(kvh * 128 + row) * 2048 + lo + col];
  }

  for (int kt = lo; kt <= q0; kt += 64) {
    __syncthreads();   // prev tile's LDS reads done (full drain; prefetch
                       // loads landed during prev compute, so vmcnt ~free)
    // ds_write staged tile from registers
#pragma unroll
    for (int t = 0; t < 4; ++t) {
      int c = t * 256 + tid, row = c >> 4, col = (c & 15) * 8;
      *(s8v*)&sK[row * 136 + col] = kreg[t];
    }
#pragma unroll
    for (int t = 0; t < 4; ++t) {
      int c = t * 256 + tid, row = c >> 3, col = (c & 7) * 8;
      *(s8v*)&sVt[row * 72 + col] = vreg[t];
    }
    // issue NEXT tile's global loads (fly under this tile's compute)
    if (kt + 64 <= q0) {
#pragma unroll
      for (int t = 0; t < 4; ++t) {
        int c = t * 256 + tid, row = c >> 4, col = (c & 15) * 8;
        kreg[t] = *(const s8v*)&Kb[(size_t)(kt + 64 + row) * 1024 + kvh * 128 + col];
      }
#pragma unroll
      for (int t = 0; t < 4; ++t) {
        int c = t * 256 + tid, row = c >> 3, col = (c & 7) * 8;
        vreg[t] = *(const s8v*)&Vt[(size_t)(kvh * 128 + row) * 2048 + kt + 64 + col];
      }
    }
    // ds_writes visible block-wide without draining vmcnt:
    asm volatile("s_waitcnt lgkmcnt(0)" ::: "memory");
    __builtin_amdgcn_sched_barrier(0);
    __builtin_amdgcn_s_barrier();

    // scores^T for 4 half-tiles of 16 keys: element (key=quad*4+r, q=ln)
    f4v sc[4];
    bool dead[4];
#pragma unroll
    for (int h4 = 0; h4 < 4; ++h4) {
      const int kb16 = kt + h4 * 16;
      dead[h4] = (kb16 > qw + 15) || (kb16 + 15 < qw - (WINDOW - 1));
      if (dead[h4]) {
#pragma unroll
        for (int r = 0; r < 4; ++r) sc[h4][r] = -1e30f;
        continue;
      }
      f4v s;
#pragma unroll
      for (int r = 0; r < 4; ++r) s[r] = 0.0f;
      __builtin_amdgcn_s_setprio(1);
#pragma unroll
      for (int kb = 0; kb < 4; ++kb) {
        s8v kf = *(const s8v*)&sK[(h4 * 16 + ln) * 136 + kb * 32 + quad * 8];
        s = MFMA16x32(kf, qf[kb], s);   // A=K rows (m=key), B=Q (n=q)
      }
      __builtin_amdgcn_s_setprio(0);
      const bool full = (kb16 + 15 <= qw) && (qw + 15 - kb16 <= WINDOW - 1);
      if (!full) {
        int base = qi - kb16 - quad * 4;   // qi - key for r=0
#pragma unroll
        for (int r = 0; r < 4; ++r)
          s[r] = ((unsigned)(base - r) <= (WINDOW - 1)) ? s[r] : -1e30f;
      }
      sc[h4] = s;
    }

    // online softmax: per-lane column q=ln; reduce 16 in-lane + 2 shfl
    float mn = m_v;
#pragma unroll
    for (int h4 = 0; h4 < 4; ++h4)
#pragma unroll
      for (int r = 0; r < 4; ++r) mn = fmaxf(mn, sc[h4][r]);
    mn = fmaxf(mn, __shfl_xor(mn, 16));
    mn = fmaxf(mn, __shfl_xor(mn, 32));

    float alpha = __expf(m_v - mn);
    m_v = mn;
    l_v *= alpha;
#pragma unroll
    for (int j = 0; j < 8; ++j)
#pragma unroll
      for (int r = 0; r < 4; ++r) accO[j][r] *= alpha;

    float lsum = 0.0f;
#pragma unroll
    for (int h4 = 0; h4 < 4; ++h4) {
      float p[4];
#pragma unroll
      for (int r = 0; r < 4; ++r) p[r] = __expf(sc[h4][r] - mn);
      lsum += (p[0] + p[1]) + (p[2] + p[3]);
      u16 pb[4] = { f2bf(p[0]), f2bf(p[1]), f2bf(p[2]), f2bf(p[3]) };
      *(s4v*)&sP[w][ln * 72 + h4 * 16 + quad * 4] = *(const s4v*)pb;
    }
    lsum += __shfl_xor(lsum, 16);
    lsum += __shfl_xor(lsum, 32);
    l_v += lsum;

    // sP is per-wave: within-wave DS write->read ordering only (rule 18)
    asm volatile("s_waitcnt lgkmcnt(0)" ::: "memory");
    __builtin_amdgcn_sched_barrier(0);

    // PV: A = V^T rows (m=d), B = P (n=q), k = 32-key chunks
#pragma unroll
    for (int c2 = 0; c2 < 2; ++c2) {
      if (dead[2 * c2] && dead[2 * c2 + 1]) continue;
      s8v pf = *(const s8v*)&sP[w][ln * 72 + c2 * 32 + quad * 8];
      __builtin_amdgcn_s_setprio(1);
#pragma unroll
      for (int j = 0; j < 8; ++j) {
        s8v vf = *(const s8v*)&sVt[(j * 16 + ln) * 72 + c2 * 32 + quad * 8];
        accO[j] = MFMA16x32(vf, pf, accO[j]);
      }
      __builtin_amdgcn_s_setprio(0);
    }
  }

  // epilogue: O^T (d rows, q cols) -> LDS transpose -> coalesced store
  __syncthreads();                    // all waves done with sK/sVt (cross-wave)
  u16* sO = sK;                       // reuse: [64 q-rows][136]
  const float rl = 1.0f / l_v;
#pragma unroll
  for (int j = 0; j < 8; ++j) {
    u16 ob[4] = { f2bf(accO[j][0] * rl), f2bf(accO[j][1] * rl),
                  f2bf(accO[j][2] * rl), f2bf(accO[j][3] * rl) };
    *(s4v*)&sO[(w * 16 + ln) * 136 + j * 16 + quad * 4] = *(const s4v*)ob;
  }
  // readback touches only this wave's rows: wave-local ordering suffices
  asm volatile("s_waitcnt lgkmcnt(0)" ::: "memory");
  __builtin_amdgcn_sched_barrier(0);
  {
    int row = lane >> 2, cc = lane & 3;
#pragma unroll
    for (int i = 0; i < 4; ++i) {
      s8v v = *(const s8v*)&sO[(w * 16 + row) * 136 + cc * 8 + i * 32];
      *(s8v*)&O[(size_t)(q0 + w * 16 + row) * 4096 + h * 128 + cc * 8 + i * 32] = v;
    }
  }
}

// ---------------------------------------------------------------------------
// Launch. Workspace peak = 92,274,688 B (round-2 proven footprint).
// Phase-aliased layout:
//   Region X [0, 48 MB):       qkv_w bf16 (dies after gemm1)
//                              -> qb@0 kb@16M vt@24M attn@28M (44 MB)
//   Region Y [48 MB, 88 MB):   hidden bf16 @48M + qkvb @64M (dies after
//                              transpose_v) -> o_w bf16 @48M (32 MB)
// ORDER CONSTRAINT: transpose_v reads qkvb, so cvt(o_w) (which overwrites
// [64,80M) = part of qkvb) must run AFTER it.
// ---------------------------------------------------------------------------
extern "C" void kernel_launch(void* const* d_in, const int* in_sizes, int n_in,
                              void* d_out, int out_size, void* d_ws, size_t ws_size,
                              hipStream_t stream) {
  const float* hidden    = (const float*)d_in[0];
  const int*   positions = (const int*)d_in[1];
  const float* qkv_w     = (const float*)d_in[2];
  const float* qkv_b     = (const float*)d_in[3];
  const float* o_w       = (const float*)d_in[4];
  const float* o_b       = (const float*)d_in[5];
  const float* sinks     = (const float*)d_in[6];

  char* ws = (char*)d_ws;
  // Region X
  u16* wW   = (u16*)ws;                         // 48 MB (phase A)
  u16* qb   = (u16*)ws;                         // 16 MB (phase B)
  u16* kb   = (u16*)(ws + 16777216ull);         //  4 MB
  u16* vt   = (u16*)(ws + 25165824ull);         //  4 MB
  u16* attn = (u16*)(ws + 29360128ull);         // 16 MB (ends 45 MB)
  // Region Y
  u16* hb   = (u16*)(ws + 50331648ull);         // 16 MB (phase A)
  u16* qkvb = (u16*)(ws + 67108864ull);         // 24 MB (ends 92,274,688)
  u16* oWb  = (u16*)(ws + 50331648ull);         // 32 MB (phase B, ends 84 MB)

  cvt_fused<<<32768, 256, 0, stream>>>(hidden, qkv_w, hb, wW);

  gemm_bt<1><<<dim3(QKV_N / 256, S_LEN / 128), 512, 0, stream>>>(
      hb, wW, qkv_b, (void*)qkvb, S_LEN, QKV_N, HID);   // wW, hb die here

  rope_split<<<S_LEN, 256, 0, stream>>>(qkvb, positions, qb, kb);

  transpose_v<<<dim3(32, 16), 256, 0, stream>>>(qkvb, vt);  // qkvb dies here

  cvt_bf16<<<16384, 256, 0, stream>>>(o_w, oWb);        // 4096*4096, region Y reuse

  attn_fwd<<<dim3(S_LEN / 64, NH), 256, 0, stream>>>(qb, kb, vt, sinks, attn);

  gemm_bt<0><<<dim3(HID / 256, S_LEN / 128), 512, 0, stream>>>(
      attn, oWb, o_b, d_out, S_LEN, HID, HID);
}